// Round 2
// baseline (868.124 us; speedup 1.0000x reference)
//
#include <hip/hip_runtime.h>
#include <stdint.h>

// ---------- common helpers ----------
typedef __attribute__((ext_vector_type(8))) short bf16x8v;   // 8 bf16 in 4 VGPRs
typedef __attribute__((ext_vector_type(4))) float f32x4;

__device__ __forceinline__ float bf2f(unsigned short u) {
  return __uint_as_float(((unsigned int)u) << 16);
}
__device__ __forceinline__ unsigned short f2bf(float f) {
  unsigned int u = __float_as_uint(f);
  u = u + 0x7fffu + ((u >> 16) & 1u);   // RNE
  return (unsigned short)(u >> 16);
}

#define NCH 32   // scan chunks
#define LCH 64   // steps per chunk (32*64 = 2048 = L)

// ---------- f32 -> bf16 conversion (float4 vectorized) ----------
__global__ void cvt_f2bf_k(const float* __restrict__ in, unsigned short* __restrict__ out) {
  int i = blockIdx.x * 256 + threadIdx.x;
  float4 v = ((const float4*)in)[i];
  union { unsigned short u[4]; uint2 p; } o;
  o.u[0] = f2bf(v.x); o.u[1] = f2bf(v.y); o.u[2] = f2bf(v.z); o.u[3] = f2bf(v.w);
  ((uint2*)out)[i] = o.p;
}

// ---------- MFMA GEMM: C[M,N] = A[M,K](bf16) @ B[N,K](bf16)^T ----------
// m97-style: 2-barrier K-loop, BK=32, global_load_lds width 16.
template<int BM, int BN, int WR, int WC, bool F32OUT>
__global__ __launch_bounds__(256) void gemm_bt(const unsigned short* __restrict__ A,
                                               const unsigned short* __restrict__ B,
                                               void* __restrict__ Cout,
                                               int M, int N, int K) {
  constexpr int BK = 32;
  __shared__ __align__(16) unsigned short lA[BM * BK];
  __shared__ __align__(16) unsigned short lB[BN * BK];
  const int tid = threadIdx.x;
  const int w = tid >> 6, lane = tid & 63;
  const int wr = w / WC, wc = w % WC;
  constexpr int WM = BM / WR, WN = BN / WC;
  constexpr int FM = WM / 16, FN = WN / 16;
  const int bm0 = blockIdx.x * BM, bn0 = blockIdx.y * BN;
  const int r16 = lane & 15, g4 = lane >> 4;

  f32x4 acc[FM][FN];
#pragma unroll
  for (int m = 0; m < FM; m++)
#pragma unroll
    for (int n = 0; n < FN; n++) acc[m][n] = {0.f, 0.f, 0.f, 0.f};

  for (int k0 = 0; k0 < K; k0 += BK) {
#pragma unroll
    for (int i = 0; i < BM / 64; i++) {
      int c = tid + i * 256;
      int row = c >> 2, kp = (c & 3) * 8;
      __builtin_amdgcn_global_load_lds(
          (const __attribute__((address_space(1))) unsigned int*)(A + (size_t)(bm0 + row) * K + k0 + kp),
          (__attribute__((address_space(3))) unsigned int*)(&lA[c * 8]), 16, 0, 0);
    }
#pragma unroll
    for (int i = 0; i < BN / 64; i++) {
      int c = tid + i * 256;
      int row = c >> 2, kp = (c & 3) * 8;
      __builtin_amdgcn_global_load_lds(
          (const __attribute__((address_space(1))) unsigned int*)(B + (size_t)(bn0 + row) * K + k0 + kp),
          (__attribute__((address_space(3))) unsigned int*)(&lB[c * 8]), 16, 0, 0);
    }
    __syncthreads();   // compiler emits vmcnt(0) drain before s_barrier

    bf16x8v af[FM], bfr[FN];
#pragma unroll
    for (int m = 0; m < FM; m++)
      af[m] = *(const bf16x8v*)&lA[(wr * WM + m * 16 + r16) * BK + g4 * 8];
#pragma unroll
    for (int n = 0; n < FN; n++)
      bfr[n] = *(const bf16x8v*)&lB[(wc * WN + n * 16 + r16) * BK + g4 * 8];
#pragma unroll
    for (int m = 0; m < FM; m++)
#pragma unroll
      for (int n = 0; n < FN; n++)
        acc[m][n] = __builtin_amdgcn_mfma_f32_16x16x32_bf16(af[m], bfr[n], acc[m][n], 0, 0, 0);
    __syncthreads();
  }

  // C/D layout: col = lane&15, row = (lane>>4)*4 + reg  [m89-verified]
#pragma unroll
  for (int m = 0; m < FM; m++) {
#pragma unroll
    for (int n = 0; n < FN; n++) {
      int col = bn0 + wc * WN + n * 16 + r16;
#pragma unroll
      for (int r = 0; r < 4; r++) {
        int row = bm0 + wr * WM + m * 16 + g4 * 4 + r;
        float v = acc[m][n][r];
        if (F32OUT) ((float*)Cout)[(size_t)row * N + col] = v;
        else        ((unsigned short*)Cout)[(size_t)row * N + col] = f2bf(v);
      }
    }
  }
}

// ---------- depthwise causal conv (k=4) + silu; branch-time output ----------
template<bool REV>
__global__ void conv_silu_k(const unsigned short* __restrict__ xz,   // [B*L, 2048] bf16, xin = cols 0..1023
                            const float* __restrict__ w,             // [1024,4] f32
                            const float* __restrict__ bias,          // [1024] f32
                            unsigned short* __restrict__ xc) {       // [B*L, 1024] bf16, branch-time
  int idx = blockIdx.x * 256 + threadIdx.x;       // 4*2048*1024
  int d = idx & 1023;
  int m = idx >> 10;
  int b = m >> 11, tau = m & 2047;
  float acc = bias[d];
#pragma unroll
  for (int j = 0; j < 4; j++) {
    int s = tau - 3 + j;
    if (s >= 0) {
      int to = REV ? (2047 - s) : s;
      acc += w[d * 4 + j] * bf2f(xz[((size_t)(b * 2048 + to)) * 2048 + d]);
    }
  }
  float sg = 1.f / (1.f + __expf(-acc));
  xc[(size_t)m * 1024 + d] = f2bf(acc * sg);
}

// ---------- dt = softplus(dbl[:, :32] @ Wdt^T + b) ----------
__global__ void dtproj_k(const float* __restrict__ dbl,    // [B*L, 64] f32
                         const float* __restrict__ W,      // [1024, 32] f32
                         const float* __restrict__ bias,   // [1024] f32
                         unsigned short* __restrict__ dt) {// [B*L, 1024] bf16
  int idx = blockIdx.x * 256 + threadIdx.x;
  int col = idx & 1023;
  int m = idx >> 10;
  const float* dr = dbl + (size_t)m * 64;
  float acc = bias[col];
#pragma unroll
  for (int k = 0; k < 32; k++) acc += dr[k] * W[col * 32 + k];
  float sp = (acc > 20.f) ? acc : log1pf(__expf(acc));
  dt[(size_t)m * 1024 + col] = f2bf(sp);
}

// ---------- scan pass1: per (b,d,chunk) compute P = prod(dA), q = partial h (h0=0) ----------
__global__ void scan_p1(const unsigned short* __restrict__ dt,
                        const unsigned short* __restrict__ xc,
                        const float* __restrict__ dbl,
                        const float* __restrict__ alog,    // [1024,16] f32
                        float* __restrict__ pq) {          // [B][NCH][32][1024]
  int idx = blockIdx.x * 256 + threadIdx.x;   // 4*32*1024
  int d = idx & 1023;
  int c = (idx >> 10) & 31;
  int b = idx >> 15;
  float a[16];
#pragma unroll
  for (int n = 0; n < 16; n++) a[n] = -__expf(alog[d * 16 + n]);
  float h[16], P[16];
#pragma unroll
  for (int n = 0; n < 16; n++) { h[n] = 0.f; P[n] = 1.f; }
  int mb = b * 2048 + c * LCH;
  for (int t = 0; t < LCH; t++) {
    size_t m = (size_t)(mb + t);
    float dtv = bf2f(dt[m * 1024 + d]);
    float xv  = bf2f(xc[m * 1024 + d]);
    float dtx = dtv * xv;
    const float* bp = dbl + m * 64 + 32;
    float Bv[16];
    *(float4*)&Bv[0]  = *(const float4*)(bp);
    *(float4*)&Bv[4]  = *(const float4*)(bp + 4);
    *(float4*)&Bv[8]  = *(const float4*)(bp + 8);
    *(float4*)&Bv[12] = *(const float4*)(bp + 12);
#pragma unroll
    for (int n = 0; n < 16; n++) {
      float dA = __expf(dtv * a[n]);
      h[n] = dA * h[n] + dtx * Bv[n];
      P[n] *= dA;
    }
  }
  float* o = pq + ((size_t)(b * NCH + c) * 32) * 1024 + d;
#pragma unroll
  for (int n = 0; n < 16; n++) {
    o[(size_t)n * 1024] = P[n];
    o[(size_t)(16 + n) * 1024] = h[n];
  }
}

// ---------- scan pass2: sequential chunk combine -> per-chunk initial h ----------
__global__ void scan_p2(const float* __restrict__ pq, float* __restrict__ hinit) {
  int idx = blockIdx.x * 256 + threadIdx.x;   // 4*16*1024
  int d = idx & 1023;
  int n = (idx >> 10) & 15;
  int b = idx >> 14;
  float h = 0.f;
  for (int c = 0; c < NCH; c++) {
    size_t pbase = ((size_t)(b * NCH + c) * 32) * 1024 + d;
    hinit[((size_t)(b * NCH + c) * 16 + n) * 1024 + d] = h;
    h = pq[pbase + (size_t)n * 1024] * h + pq[pbase + (size_t)(16 + n) * 1024];
  }
}

// ---------- scan pass3: replay with h0, fuse +xc*D and *silu(z); write original time ----------
template<bool REV, bool ADD>
__global__ void scan_p3(const unsigned short* __restrict__ dt,
                        const unsigned short* __restrict__ xc,
                        const float* __restrict__ dbl,
                        const float* __restrict__ alog,
                        const float* __restrict__ Dp,              // [1024] f32
                        const unsigned short* __restrict__ xz,     // z = cols 1024..2047 (bf16)
                        const float* __restrict__ hinit,
                        float* __restrict__ ysum) {                // [B*L, 1024] f32, original time
  int idx = blockIdx.x * 256 + threadIdx.x;
  int d = idx & 1023;
  int c = (idx >> 10) & 31;
  int b = idx >> 15;
  float a[16];
#pragma unroll
  for (int n = 0; n < 16; n++) a[n] = -__expf(alog[d * 16 + n]);
  float h[16];
#pragma unroll
  for (int n = 0; n < 16; n++) h[n] = hinit[((size_t)(b * NCH + c) * 16 + n) * 1024 + d];
  float Dv = Dp[d];
  int mb = b * 2048 + c * LCH;
  for (int t = 0; t < LCH; t++) {
    size_t m = (size_t)(mb + t);
    float dtv = bf2f(dt[m * 1024 + d]);
    float xv  = bf2f(xc[m * 1024 + d]);
    float dtx = dtv * xv;
    const float* bp = dbl + m * 64 + 32;
    float Bv[16], Cv[16];
    *(float4*)&Bv[0]  = *(const float4*)(bp);
    *(float4*)&Bv[4]  = *(const float4*)(bp + 4);
    *(float4*)&Bv[8]  = *(const float4*)(bp + 8);
    *(float4*)&Bv[12] = *(const float4*)(bp + 12);
    *(float4*)&Cv[0]  = *(const float4*)(bp + 16);
    *(float4*)&Cv[4]  = *(const float4*)(bp + 20);
    *(float4*)&Cv[8]  = *(const float4*)(bp + 24);
    *(float4*)&Cv[12] = *(const float4*)(bp + 28);
    float y = 0.f;
#pragma unroll
    for (int n = 0; n < 16; n++) {
      float dA = __expf(dtv * a[n]);
      h[n] = dA * h[n] + dtx * Bv[n];
      y += h[n] * Cv[n];
    }
    y += xv * Dv;
    int tau = c * LCH + t;
    int to = REV ? (2047 - tau) : tau;
    size_t mo = (size_t)b * 2048 + to;
    float zv = bf2f(xz[mo * 2048 + 1024 + d]);
    float gt = zv / (1.f + __expf(-zv));
    float val = y * gt;
    if (ADD) ysum[mo * 1024 + d] += val;
    else     ysum[mo * 1024 + d] = val;
  }
}

// ---------- f32 -> bf16 convert for ysum ----------
__global__ void f2bf_k(const float* __restrict__ in, unsigned short* __restrict__ out) {
  int i = blockIdx.x * 256 + threadIdx.x;
  float4 v = ((const float4*)in)[i];
  union { unsigned short u[4]; uint2 p; } o;
  o.u[0] = f2bf(v.x); o.u[1] = f2bf(v.y); o.u[2] = f2bf(v.z); o.u[3] = f2bf(v.w);
  ((uint2*)out)[i] = o.p;
}

// ---------- layernorm(512) + residual; one wave per row; all f32 ----------
__global__ void ln_res_k(const float* __restrict__ yt,   // [B*L, 512] f32
                         const float* __restrict__ x,    // [B*L, 512] f32
                         const float* __restrict__ g,    // [512]
                         const float* __restrict__ bta,  // [512]
                         float* __restrict__ out) {      // [B*L, 512] f32
  int m = blockIdx.x;
  int l = threadIdx.x;   // 0..63
  const float* yr = yt + (size_t)m * 512 + l * 8;
  float vv[8];
  *(float4*)&vv[0] = *(const float4*)yr;
  *(float4*)&vv[4] = *(const float4*)(yr + 4);
  float s = 0.f, ss = 0.f;
#pragma unroll
  for (int j = 0; j < 8; j++) { s += vv[j]; ss += vv[j] * vv[j]; }
#pragma unroll
  for (int o = 32; o > 0; o >>= 1) { s += __shfl_xor(s, o); ss += __shfl_xor(ss, o); }
  float mu = s * (1.f / 512.f);
  float var = ss * (1.f / 512.f) - mu * mu;
  float rstd = rsqrtf(var + 1e-6f);
  const float* xr = x + (size_t)m * 512 + l * 8;
  float xv[8];
  *(float4*)&xv[0] = *(const float4*)xr;
  *(float4*)&xv[4] = *(const float4*)(xr + 4);
  float ov[8];
#pragma unroll
  for (int j = 0; j < 8; j++) {
    int d = l * 8 + j;
    ov[j] = xv[j] + (vv[j] - mu) * rstd * g[d] + bta[d];
  }
  float* orow = out + (size_t)m * 512 + l * 8;
  *(float4*)orow = *(float4*)&ov[0];
  *(float4*)(orow + 4) = *(float4*)&ov[4];
}

// ---------- launcher ----------
extern "C" void kernel_launch(void* const* d_in, const int* in_sizes, int n_in,
                              void* d_out, int out_size, void* d_ws, size_t ws_size,
                              hipStream_t stream) {
  const float* x_f32   = (const float*)d_in[0];
  const float* w_in_f  = (const float*)d_in[1];
  const float* w_out_f = (const float*)d_in[2];
  const float* ln_g    = (const float*)d_in[17];
  const float* ln_b    = (const float*)d_in[18];

  char* ws = (char*)d_ws;
  unsigned short* XB  = (unsigned short*)(ws + 0);           // [8192,512] bf16    8 MiB
  unsigned short* W1B = (unsigned short*)(ws + 8388608);     // [2048,512] bf16    2 MiB
  unsigned short* W2B = (unsigned short*)(ws + 10485760);    // [512,1024] bf16    1 MiB
  unsigned short* XPB = (unsigned short*)(ws + 11534336);    // [64,1024]  bf16  128 KiB
  unsigned short* XZ  = (unsigned short*)(ws + 11665408);    // [8192,2048] bf16  32 MiB
  unsigned short* XC  = (unsigned short*)(ws + 45219840);    // [8192,1024] bf16  16 MiB
  unsigned short* DT  = (unsigned short*)(ws + 61997056);    // [8192,1024] bf16  16 MiB (reused as YSB)
  float*          DBL = (float*)(ws + 78774272);             // [8192,64]  f32     2 MiB
  float*          YSUM= (float*)(ws + 80871424);             // [8192,1024] f32   32 MiB
  float*          PQ  = (float*)(ws + 114425856);            // 16 MiB (reused as YT)
  float*          HIN = (float*)(ws + 131203072);            //  8 MiB
  unsigned short* YSB = DT;                                  // reuse DT after scans
  float*          YT  = PQ;                                  // reuse PQ after scans

  const int M = 8192;

  // convert GEMM operands to bf16
  cvt_f2bf_k<<<4096, 256, 0, stream>>>(x_f32, XB);        // 8192*512
  cvt_f2bf_k<<<1024, 256, 0, stream>>>(w_in_f, W1B);      // 2048*512
  cvt_f2bf_k<<< 512, 256, 0, stream>>>(w_out_f, W2B);     // 512*1024

  // xz = x @ in_proj_w^T   [8192, 2048]
  gemm_bt<128, 128, 2, 2, false><<<dim3(64, 16), 256, 0, stream>>>(XB, W1B, (void*)XZ, M, 2048, 512);

  for (int br = 0; br < 2; br++) {
    const float* cw    = (const float*)d_in[3 + br * 7];
    const float* cb    = (const float*)d_in[4 + br * 7];
    const float* xproj = (const float*)d_in[5 + br * 7];
    const float* dtw   = (const float*)d_in[6 + br * 7];
    const float* dtb   = (const float*)d_in[7 + br * 7];
    const float* alog  = (const float*)d_in[8 + br * 7];
    const float* Dp    = (const float*)d_in[9 + br * 7];

    cvt_f2bf_k<<<64, 256, 0, stream>>>(xproj, XPB);       // 64*1024

    if (br == 0) conv_silu_k<false><<<32768, 256, 0, stream>>>(XZ, cw, cb, XC);
    else         conv_silu_k<true ><<<32768, 256, 0, stream>>>(XZ, cw, cb, XC);

    // dbl = xc @ xproj^T  [8192, 64]
    gemm_bt<128, 64, 4, 1, true><<<dim3(64, 1), 256, 0, stream>>>(XC, XPB, (void*)DBL, M, 64, 1024);

    dtproj_k<<<32768, 256, 0, stream>>>(DBL, dtw, dtb, DT);

    scan_p1<<<512, 256, 0, stream>>>(DT, XC, DBL, alog, PQ);
    scan_p2<<<256, 256, 0, stream>>>(PQ, HIN);
    if (br == 0) scan_p3<false, false><<<512, 256, 0, stream>>>(DT, XC, DBL, alog, Dp, XZ, HIN, YSUM);
    else         scan_p3<true,  true ><<<512, 256, 0, stream>>>(DT, XC, DBL, alog, Dp, XZ, HIN, YSUM);
  }

  // ysum -> bf16 (into YSB = DT region; DT no longer needed)
  f2bf_k<<<8192, 256, 0, stream>>>(YSUM, YSB);

  // yt = ysum @ out_proj^T  [8192, 512] f32 (into YT = PQ region)
  gemm_bt<128, 128, 2, 2, true><<<dim3(64, 4), 256, 0, stream>>>(YSB, W2B, (void*)YT, M, 512, 1024);

  // out = x + layernorm(yt)
  ln_res_k<<<8192, 64, 0, stream>>>(YT, x_f32, ln_g, ln_b, (float*)d_out);
}

// Round 3
// 661.231 us; speedup vs baseline: 1.3129x; 1.3129x over previous
//
#include <hip/hip_runtime.h>
#include <stdint.h>

// ---------- common helpers ----------
typedef __attribute__((ext_vector_type(8))) short bf16x8v;   // 8 bf16 in 4 VGPRs
typedef __attribute__((ext_vector_type(4))) float f32x4;

__device__ __forceinline__ float bf2f(unsigned short u) {
  return __uint_as_float(((unsigned int)u) << 16);
}
__device__ __forceinline__ unsigned short f2bf(float f) {
  unsigned int u = __float_as_uint(f);
  u = u + 0x7fffu + ((u >> 16) & 1u);   // RNE
  return (unsigned short)(u >> 16);
}

#define NCH 32   // scan chunks
#define LCH 64   // steps per chunk (32*64 = 2048 = L)

// ---------- f32 -> bf16 conversion (float4 vectorized) ----------
__global__ void cvt_f2bf_k(const float* __restrict__ in, unsigned short* __restrict__ out) {
  int i = blockIdx.x * 256 + threadIdx.x;
  float4 v = ((const float4*)in)[i];
  union { unsigned short u[4]; uint2 p; } o;
  o.u[0] = f2bf(v.x); o.u[1] = f2bf(v.y); o.u[2] = f2bf(v.z); o.u[3] = f2bf(v.w);
  ((uint2*)out)[i] = o.p;
}

// ---------- MFMA GEMM: C[M,N] = A[M,K](bf16) @ B[N,K](bf16)^T ----------
template<int BM, int BN, int WR, int WC, bool F32OUT>
__global__ __launch_bounds__(256) void gemm_bt(const unsigned short* __restrict__ A,
                                               const unsigned short* __restrict__ B,
                                               void* __restrict__ Cout,
                                               int M, int N, int K) {
  constexpr int BK = 32;
  __shared__ __align__(16) unsigned short lA[BM * BK];
  __shared__ __align__(16) unsigned short lB[BN * BK];
  const int tid = threadIdx.x;
  const int w = tid >> 6, lane = tid & 63;
  const int wr = w / WC, wc = w % WC;
  constexpr int WM = BM / WR, WN = BN / WC;
  constexpr int FM = WM / 16, FN = WN / 16;
  const int bm0 = blockIdx.x * BM, bn0 = blockIdx.y * BN;
  const int r16 = lane & 15, g4 = lane >> 4;

  f32x4 acc[FM][FN];
#pragma unroll
  for (int m = 0; m < FM; m++)
#pragma unroll
    for (int n = 0; n < FN; n++) acc[m][n] = {0.f, 0.f, 0.f, 0.f};

  for (int k0 = 0; k0 < K; k0 += BK) {
#pragma unroll
    for (int i = 0; i < BM / 64; i++) {
      int c = tid + i * 256;
      int row = c >> 2, kp = (c & 3) * 8;
      __builtin_amdgcn_global_load_lds(
          (const __attribute__((address_space(1))) unsigned int*)(A + (size_t)(bm0 + row) * K + k0 + kp),
          (__attribute__((address_space(3))) unsigned int*)(&lA[c * 8]), 16, 0, 0);
    }
#pragma unroll
    for (int i = 0; i < BN / 64; i++) {
      int c = tid + i * 256;
      int row = c >> 2, kp = (c & 3) * 8;
      __builtin_amdgcn_global_load_lds(
          (const __attribute__((address_space(1))) unsigned int*)(B + (size_t)(bn0 + row) * K + k0 + kp),
          (__attribute__((address_space(3))) unsigned int*)(&lB[c * 8]), 16, 0, 0);
    }
    __syncthreads();

    bf16x8v af[FM], bfr[FN];
#pragma unroll
    for (int m = 0; m < FM; m++)
      af[m] = *(const bf16x8v*)&lA[(wr * WM + m * 16 + r16) * BK + g4 * 8];
#pragma unroll
    for (int n = 0; n < FN; n++)
      bfr[n] = *(const bf16x8v*)&lB[(wc * WN + n * 16 + r16) * BK + g4 * 8];
#pragma unroll
    for (int m = 0; m < FM; m++)
#pragma unroll
      for (int n = 0; n < FN; n++)
        acc[m][n] = __builtin_amdgcn_mfma_f32_16x16x32_bf16(af[m], bfr[n], acc[m][n], 0, 0, 0);
    __syncthreads();
  }

  // C/D layout: col = lane&15, row = (lane>>4)*4 + reg  [m89-verified]
#pragma unroll
  for (int m = 0; m < FM; m++) {
#pragma unroll
    for (int n = 0; n < FN; n++) {
      int col = bn0 + wc * WN + n * 16 + r16;
#pragma unroll
      for (int r = 0; r < 4; r++) {
        int row = bm0 + wr * WM + m * 16 + g4 * 4 + r;
        float v = acc[m][n][r];
        if (F32OUT) ((float*)Cout)[(size_t)row * N + col] = v;
        else        ((unsigned short*)Cout)[(size_t)row * N + col] = f2bf(v);
      }
    }
  }
}

// ---------- depthwise causal conv (k=4) + silu; branch-time output ----------
template<bool REV>
__global__ void conv_silu_k(const unsigned short* __restrict__ xz,   // [B*L, 2048] bf16, xin = cols 0..1023
                            const float* __restrict__ w,             // [1024,4] f32
                            const float* __restrict__ bias,          // [1024] f32
                            unsigned short* __restrict__ xc) {       // [B*L, 1024] bf16, branch-time
  int idx = blockIdx.x * 256 + threadIdx.x;       // 4*2048*1024
  int d = idx & 1023;
  int m = idx >> 10;
  int b = m >> 11, tau = m & 2047;
  float acc = bias[d];
#pragma unroll
  for (int j = 0; j < 4; j++) {
    int s = tau - 3 + j;
    if (s >= 0) {
      int to = REV ? (2047 - s) : s;
      acc += w[d * 4 + j] * bf2f(xz[((size_t)(b * 2048 + to)) * 2048 + d]);
    }
  }
  float sg = 1.f / (1.f + __expf(-acc));
  xc[(size_t)m * 1024 + d] = f2bf(acc * sg);
}

// ---------- dt = softplus(dbl[:, :32] @ Wdt^T + b) ----------
// One thread per COLUMN; W row (32 f32) held in VGPRs, amortized over DROWS rows.
// dbl row address is wave-uniform -> scalar (s_load) broadcast reads.
#define DROWS 64
__global__ __launch_bounds__(256) void dtproj_k(const float* __restrict__ dbl, // [B*L, 64] f32
                         const float* __restrict__ W,      // [1024, 32] f32
                         const float* __restrict__ bias,   // [1024] f32
                         unsigned short* __restrict__ dt) {// [B*L, 1024] bf16
  int col = blockIdx.y * 256 + threadIdx.x;
  int row0 = blockIdx.x * DROWS;
  float wv[32];
#pragma unroll
  for (int k = 0; k < 32; k += 4)
    *(float4*)&wv[k] = *(const float4*)&W[col * 32 + k];
  float bs = bias[col];
#pragma unroll 4
  for (int r = 0; r < DROWS; r++) {
    const float* dr = dbl + (size_t)(row0 + r) * 64;
    float acc = bs;
#pragma unroll
    for (int k = 0; k < 32; k++) acc += dr[k] * wv[k];
    float sp = (acc > 20.f) ? acc : log1pf(__expf(acc));
    dt[(size_t)(row0 + r) * 1024 + col] = f2bf(sp);
  }
}

// ---------- scan pass1: per (b,d,chunk) compute P = prod(dA), q = partial h (h0=0) ----------
__global__ void scan_p1(const unsigned short* __restrict__ dt,
                        const unsigned short* __restrict__ xc,
                        const float* __restrict__ dbl,
                        const float* __restrict__ alog,    // [1024,16] f32
                        float* __restrict__ pq) {          // [B][NCH][32][1024]
  int idx = blockIdx.x * 256 + threadIdx.x;   // 4*32*1024
  int d = idx & 1023;
  int c = (idx >> 10) & 31;
  int b = idx >> 15;
  float a[16];
#pragma unroll
  for (int n = 0; n < 16; n++) a[n] = -__expf(alog[d * 16 + n]);
  float h[16], P[16];
#pragma unroll
  for (int n = 0; n < 16; n++) { h[n] = 0.f; P[n] = 1.f; }
  int mb = b * 2048 + c * LCH;
  for (int t = 0; t < LCH; t++) {
    size_t m = (size_t)(mb + t);
    float dtv = bf2f(dt[m * 1024 + d]);
    float xv  = bf2f(xc[m * 1024 + d]);
    float dtx = dtv * xv;
    const float* bp = dbl + m * 64 + 32;
    float Bv[16];
    *(float4*)&Bv[0]  = *(const float4*)(bp);
    *(float4*)&Bv[4]  = *(const float4*)(bp + 4);
    *(float4*)&Bv[8]  = *(const float4*)(bp + 8);
    *(float4*)&Bv[12] = *(const float4*)(bp + 12);
#pragma unroll
    for (int n = 0; n < 16; n++) {
      float dA = __expf(dtv * a[n]);
      h[n] = dA * h[n] + dtx * Bv[n];
      P[n] *= dA;
    }
  }
  float* o = pq + ((size_t)(b * NCH + c) * 32) * 1024 + d;
#pragma unroll
  for (int n = 0; n < 16; n++) {
    o[(size_t)n * 1024] = P[n];
    o[(size_t)(16 + n) * 1024] = h[n];
  }
}

// ---------- scan pass2: sequential chunk combine -> per-chunk initial h ----------
__global__ void scan_p2(const float* __restrict__ pq, float* __restrict__ hinit) {
  int idx = blockIdx.x * 256 + threadIdx.x;   // 4*16*1024
  int d = idx & 1023;
  int n = (idx >> 10) & 15;
  int b = idx >> 14;
  float h = 0.f;
  for (int c = 0; c < NCH; c++) {
    size_t pbase = ((size_t)(b * NCH + c) * 32) * 1024 + d;
    hinit[((size_t)(b * NCH + c) * 16 + n) * 1024 + d] = h;
    h = pq[pbase + (size_t)n * 1024] * h + pq[pbase + (size_t)(16 + n) * 1024];
  }
}

// ---------- scan pass3: replay with h0, fuse +xc*D and *silu(z); write original time ----------
template<bool REV, bool ADD>
__global__ void scan_p3(const unsigned short* __restrict__ dt,
                        const unsigned short* __restrict__ xc,
                        const float* __restrict__ dbl,
                        const float* __restrict__ alog,
                        const float* __restrict__ Dp,              // [1024] f32
                        const unsigned short* __restrict__ xz,     // z = cols 1024..2047 (bf16)
                        const float* __restrict__ hinit,
                        float* __restrict__ ysum) {                // [B*L, 1024] f32, original time
  int idx = blockIdx.x * 256 + threadIdx.x;
  int d = idx & 1023;
  int c = (idx >> 10) & 31;
  int b = idx >> 15;
  float a[16];
#pragma unroll
  for (int n = 0; n < 16; n++) a[n] = -__expf(alog[d * 16 + n]);
  float h[16];
#pragma unroll
  for (int n = 0; n < 16; n++) h[n] = hinit[((size_t)(b * NCH + c) * 16 + n) * 1024 + d];
  float Dv = Dp[d];
  int mb = b * 2048 + c * LCH;
  for (int t = 0; t < LCH; t++) {
    size_t m = (size_t)(mb + t);
    float dtv = bf2f(dt[m * 1024 + d]);
    float xv  = bf2f(xc[m * 1024 + d]);
    float dtx = dtv * xv;
    const float* bp = dbl + m * 64 + 32;
    float Bv[16], Cv[16];
    *(float4*)&Bv[0]  = *(const float4*)(bp);
    *(float4*)&Bv[4]  = *(const float4*)(bp + 4);
    *(float4*)&Bv[8]  = *(const float4*)(bp + 8);
    *(float4*)&Bv[12] = *(const float4*)(bp + 12);
    *(float4*)&Cv[0]  = *(const float4*)(bp + 16);
    *(float4*)&Cv[4]  = *(const float4*)(bp + 20);
    *(float4*)&Cv[8]  = *(const float4*)(bp + 24);
    *(float4*)&Cv[12] = *(const float4*)(bp + 28);
    float y = 0.f;
#pragma unroll
    for (int n = 0; n < 16; n++) {
      float dA = __expf(dtv * a[n]);
      h[n] = dA * h[n] + dtx * Bv[n];
      y += h[n] * Cv[n];
    }
    y += xv * Dv;
    int tau = c * LCH + t;
    int to = REV ? (2047 - tau) : tau;
    size_t mo = (size_t)b * 2048 + to;
    float zv = bf2f(xz[mo * 2048 + 1024 + d]);
    float gt = zv / (1.f + __expf(-zv));
    float val = y * gt;
    if (ADD) ysum[mo * 1024 + d] += val;
    else     ysum[mo * 1024 + d] = val;
  }
}

// ---------- f32 -> bf16 convert for ysum ----------
__global__ void f2bf_k(const float* __restrict__ in, unsigned short* __restrict__ out) {
  int i = blockIdx.x * 256 + threadIdx.x;
  float4 v = ((const float4*)in)[i];
  union { unsigned short u[4]; uint2 p; } o;
  o.u[0] = f2bf(v.x); o.u[1] = f2bf(v.y); o.u[2] = f2bf(v.z); o.u[3] = f2bf(v.w);
  ((uint2*)out)[i] = o.p;
}

// ---------- layernorm(512) + residual; one wave per row; all f32 ----------
__global__ void ln_res_k(const float* __restrict__ yt,   // [B*L, 512] f32
                         const float* __restrict__ x,    // [B*L, 512] f32
                         const float* __restrict__ g,    // [512]
                         const float* __restrict__ bta,  // [512]
                         float* __restrict__ out) {      // [B*L, 512] f32
  int m = blockIdx.x;
  int l = threadIdx.x;   // 0..63
  const float* yr = yt + (size_t)m * 512 + l * 8;
  float vv[8];
  *(float4*)&vv[0] = *(const float4*)yr;
  *(float4*)&vv[4] = *(const float4*)(yr + 4);
  float s = 0.f, ss = 0.f;
#pragma unroll
  for (int j = 0; j < 8; j++) { s += vv[j]; ss += vv[j] * vv[j]; }
#pragma unroll
  for (int o = 32; o > 0; o >>= 1) { s += __shfl_xor(s, o); ss += __shfl_xor(ss, o); }
  float mu = s * (1.f / 512.f);
  float var = ss * (1.f / 512.f) - mu * mu;
  float rstd = rsqrtf(var + 1e-6f);
  const float* xr = x + (size_t)m * 512 + l * 8;
  float xv[8];
  *(float4*)&xv[0] = *(const float4*)xr;
  *(float4*)&xv[4] = *(const float4*)(xr + 4);
  float ov[8];
#pragma unroll
  for (int j = 0; j < 8; j++) {
    int d = l * 8 + j;
    ov[j] = xv[j] + (vv[j] - mu) * rstd * g[d] + bta[d];
  }
  float* orow = out + (size_t)m * 512 + l * 8;
  *(float4*)orow = *(float4*)&ov[0];
  *(float4*)(orow + 4) = *(float4*)&ov[4];
}

// ---------- launcher ----------
extern "C" void kernel_launch(void* const* d_in, const int* in_sizes, int n_in,
                              void* d_out, int out_size, void* d_ws, size_t ws_size,
                              hipStream_t stream) {
  const float* x_f32   = (const float*)d_in[0];
  const float* w_in_f  = (const float*)d_in[1];
  const float* w_out_f = (const float*)d_in[2];
  const float* ln_g    = (const float*)d_in[17];
  const float* ln_b    = (const float*)d_in[18];

  char* ws = (char*)d_ws;
  unsigned short* XB  = (unsigned short*)(ws + 0);           // [8192,512] bf16    8 MiB
  unsigned short* W1B = (unsigned short*)(ws + 8388608);     // [2048,512] bf16    2 MiB
  unsigned short* W2B = (unsigned short*)(ws + 10485760);    // [512,1024] bf16    1 MiB
  unsigned short* XPB = (unsigned short*)(ws + 11534336);    // [64,1024]  bf16  128 KiB
  unsigned short* XZ  = (unsigned short*)(ws + 11665408);    // [8192,2048] bf16  32 MiB
  unsigned short* XC  = (unsigned short*)(ws + 45219840);    // [8192,1024] bf16  16 MiB
  unsigned short* DT  = (unsigned short*)(ws + 61997056);    // [8192,1024] bf16  16 MiB (reused as YSB)
  float*          DBL = (float*)(ws + 78774272);             // [8192,64]  f32     2 MiB
  float*          YSUM= (float*)(ws + 80871424);             // [8192,1024] f32   32 MiB
  float*          PQ  = (float*)(ws + 114425856);            // 16 MiB (reused as YT)
  float*          HIN = (float*)(ws + 131203072);            //  8 MiB
  unsigned short* YSB = DT;                                  // reuse DT after scans
  float*          YT  = PQ;                                  // reuse PQ after scans

  const int M = 8192;

  // convert GEMM operands to bf16
  cvt_f2bf_k<<<4096, 256, 0, stream>>>(x_f32, XB);        // 8192*512
  cvt_f2bf_k<<<1024, 256, 0, stream>>>(w_in_f, W1B);      // 2048*512
  cvt_f2bf_k<<< 512, 256, 0, stream>>>(w_out_f, W2B);     // 512*1024

  // xz = x @ in_proj_w^T   [8192, 2048]
  gemm_bt<128, 128, 2, 2, false><<<dim3(64, 16), 256, 0, stream>>>(XB, W1B, (void*)XZ, M, 2048, 512);

  for (int br = 0; br < 2; br++) {
    const float* cw    = (const float*)d_in[3 + br * 7];
    const float* cb    = (const float*)d_in[4 + br * 7];
    const float* xproj = (const float*)d_in[5 + br * 7];
    const float* dtw   = (const float*)d_in[6 + br * 7];
    const float* dtb   = (const float*)d_in[7 + br * 7];
    const float* alog  = (const float*)d_in[8 + br * 7];
    const float* Dp    = (const float*)d_in[9 + br * 7];

    cvt_f2bf_k<<<64, 256, 0, stream>>>(xproj, XPB);       // 64*1024

    if (br == 0) conv_silu_k<false><<<32768, 256, 0, stream>>>(XZ, cw, cb, XC);
    else         conv_silu_k<true ><<<32768, 256, 0, stream>>>(XZ, cw, cb, XC);

    // dbl = xc @ xproj^T  [8192, 64]
    gemm_bt<128, 64, 4, 1, true><<<dim3(64, 1), 256, 0, stream>>>(XC, XPB, (void*)DBL, M, 64, 1024);

    // dt = softplus(dbl[:, :32] @ dtw^T + dtb)
    dtproj_k<<<dim3(8192 / DROWS, 4), 256, 0, stream>>>(DBL, dtw, dtb, DT);

    scan_p1<<<512, 256, 0, stream>>>(DT, XC, DBL, alog, PQ);
    scan_p2<<<256, 256, 0, stream>>>(PQ, HIN);
    if (br == 0) scan_p3<false, false><<<512, 256, 0, stream>>>(DT, XC, DBL, alog, Dp, XZ, HIN, YSUM);
    else         scan_p3<true,  true ><<<512, 256, 0, stream>>>(DT, XC, DBL, alog, Dp, XZ, HIN, YSUM);
  }

  // ysum -> bf16 (into YSB = DT region; DT no longer needed)
  f2bf_k<<<8192, 256, 0, stream>>>(YSUM, YSB);

  // yt = ysum @ out_proj^T  [8192, 512] f32 (into YT = PQ region)
  gemm_bt<128, 128, 2, 2, true><<<dim3(64, 4), 256, 0, stream>>>(YSB, W2B, (void*)YT, M, 512, 1024);

  // out = x + layernorm(yt)
  ln_res_k<<<8192, 64, 0, stream>>>(YT, x_f32, ln_g, ln_b, (float*)d_out);
}

// Round 4
// 445.212 us; speedup vs baseline: 1.9499x; 1.4852x over previous
//
#include <hip/hip_runtime.h>
#include <stdint.h>

// ---------- common helpers ----------
typedef __attribute__((ext_vector_type(8))) short bf16x8v;   // 8 bf16 in 4 VGPRs
typedef __attribute__((ext_vector_type(4))) float f32x4;

__device__ __forceinline__ float bf2f(unsigned short u) {
  return __uint_as_float(((unsigned int)u) << 16);
}
__device__ __forceinline__ unsigned short f2bf(float f) {
  unsigned int u = __float_as_uint(f);
  u = u + 0x7fffu + ((u >> 16) & 1u);   // RNE
  return (unsigned short)(u >> 16);
}

#define NCH 64   // scan chunks (occupancy: 1024 blocks -> ~42%)
#define LCH 32   // steps per chunk (64*32 = 2048 = L)

// ---------- f32 -> bf16 conversion (float4 vectorized) ----------
__global__ void cvt_f2bf_k(const float* __restrict__ in, unsigned short* __restrict__ out) {
  int i = blockIdx.x * 256 + threadIdx.x;
  float4 v = ((const float4*)in)[i];
  union { unsigned short u[4]; uint2 p; } o;
  o.u[0] = f2bf(v.x); o.u[1] = f2bf(v.y); o.u[2] = f2bf(v.z); o.u[3] = f2bf(v.w);
  ((uint2*)out)[i] = o.p;
}

// ---------- MFMA GEMM: C[M,N] = A[M,K](bf16) @ B[N,K](bf16)^T ----------
template<int BM, int BN, int WR, int WC, bool F32OUT>
__global__ __launch_bounds__(256) void gemm_bt(const unsigned short* __restrict__ A,
                                               const unsigned short* __restrict__ B,
                                               void* __restrict__ Cout,
                                               int M, int N, int K) {
  constexpr int BK = 32;
  __shared__ __align__(16) unsigned short lA[BM * BK];
  __shared__ __align__(16) unsigned short lB[BN * BK];
  const int tid = threadIdx.x;
  const int w = tid >> 6, lane = tid & 63;
  const int wr = w / WC, wc = w % WC;
  constexpr int WM = BM / WR, WN = BN / WC;
  constexpr int FM = WM / 16, FN = WN / 16;
  const int bm0 = blockIdx.x * BM, bn0 = blockIdx.y * BN;
  const int r16 = lane & 15, g4 = lane >> 4;

  f32x4 acc[FM][FN];
#pragma unroll
  for (int m = 0; m < FM; m++)
#pragma unroll
    for (int n = 0; n < FN; n++) acc[m][n] = {0.f, 0.f, 0.f, 0.f};

  for (int k0 = 0; k0 < K; k0 += BK) {
#pragma unroll
    for (int i = 0; i < BM / 64; i++) {
      int c = tid + i * 256;
      int row = c >> 2, kp = (c & 3) * 8;
      __builtin_amdgcn_global_load_lds(
          (const __attribute__((address_space(1))) unsigned int*)(A + (size_t)(bm0 + row) * K + k0 + kp),
          (__attribute__((address_space(3))) unsigned int*)(&lA[c * 8]), 16, 0, 0);
    }
#pragma unroll
    for (int i = 0; i < BN / 64; i++) {
      int c = tid + i * 256;
      int row = c >> 2, kp = (c & 3) * 8;
      __builtin_amdgcn_global_load_lds(
          (const __attribute__((address_space(1))) unsigned int*)(B + (size_t)(bn0 + row) * K + k0 + kp),
          (__attribute__((address_space(3))) unsigned int*)(&lB[c * 8]), 16, 0, 0);
    }
    __syncthreads();

    bf16x8v af[FM], bfr[FN];
#pragma unroll
    for (int m = 0; m < FM; m++)
      af[m] = *(const bf16x8v*)&lA[(wr * WM + m * 16 + r16) * BK + g4 * 8];
#pragma unroll
    for (int n = 0; n < FN; n++)
      bfr[n] = *(const bf16x8v*)&lB[(wc * WN + n * 16 + r16) * BK + g4 * 8];
#pragma unroll
    for (int m = 0; m < FM; m++)
#pragma unroll
      for (int n = 0; n < FN; n++)
        acc[m][n] = __builtin_amdgcn_mfma_f32_16x16x32_bf16(af[m], bfr[n], acc[m][n], 0, 0, 0);
    __syncthreads();
  }

  // C/D layout: col = lane&15, row = (lane>>4)*4 + reg  [m89-verified]
#pragma unroll
  for (int m = 0; m < FM; m++) {
#pragma unroll
    for (int n = 0; n < FN; n++) {
      int col = bn0 + wc * WN + n * 16 + r16;
#pragma unroll
      for (int r = 0; r < 4; r++) {
        int row = bm0 + wr * WM + m * 16 + g4 * 4 + r;
        float v = acc[m][n][r];
        if (F32OUT) ((float*)Cout)[(size_t)row * N + col] = v;
        else        ((unsigned short*)Cout)[(size_t)row * N + col] = f2bf(v);
      }
    }
  }
}

// ---------- depthwise causal conv (k=4) + silu; branch-time output ----------
template<bool REV>
__global__ void conv_silu_k(const unsigned short* __restrict__ xz,   // [B*L, 2048] bf16, xin = cols 0..1023
                            const float* __restrict__ w,             // [1024,4] f32
                            const float* __restrict__ bias,          // [1024] f32
                            unsigned short* __restrict__ xc) {       // [B*L, 1024] bf16, branch-time
  int idx = blockIdx.x * 256 + threadIdx.x;       // 4*2048*1024
  int d = idx & 1023;
  int m = idx >> 10;
  int b = m >> 11, tau = m & 2047;
  float acc = bias[d];
#pragma unroll
  for (int j = 0; j < 4; j++) {
    int s = tau - 3 + j;
    if (s >= 0) {
      int to = REV ? (2047 - s) : s;
      acc += w[d * 4 + j] * bf2f(xz[((size_t)(b * 2048 + to)) * 2048 + d]);
    }
  }
  float sg = 1.f / (1.f + __expf(-acc));
  xc[(size_t)m * 1024 + d] = f2bf(acc * sg);
}

// ---------- dt = softplus(dbl[:, :32] @ Wdt^T + b) ----------
#define DROWS 64
__global__ __launch_bounds__(256) void dtproj_k(const float* __restrict__ dbl, // [B*L, 64] f32
                         const float* __restrict__ W,      // [1024, 32] f32
                         const float* __restrict__ bias,   // [1024] f32
                         unsigned short* __restrict__ dt) {// [B*L, 1024] bf16
  int col = blockIdx.y * 256 + threadIdx.x;
  int row0 = blockIdx.x * DROWS;
  float wv[32];
#pragma unroll
  for (int k = 0; k < 32; k += 4)
    *(float4*)&wv[k] = *(const float4*)&W[col * 32 + k];
  float bs = bias[col];
#pragma unroll 4
  for (int r = 0; r < DROWS; r++) {
    const float* dr = dbl + (size_t)(row0 + r) * 64;
    float acc = bs;
#pragma unroll
    for (int k = 0; k < 32; k++) acc += dr[k] * wv[k];
    float sp = (acc > 20.f) ? acc : log1pf(__expf(acc));
    dt[(size_t)(row0 + r) * 1024 + col] = f2bf(sp);
  }
}

// ---------- scan pass1: per (b,d,chunk) compute P = prod(dA), q = partial h (h0=0) ----------
// pq layout: [B][NCH][32][1024]; slots 0..15 = P, 16..31 = q.
__global__ void scan_p1(const unsigned short* __restrict__ dt,
                        const unsigned short* __restrict__ xc,
                        const float* __restrict__ dbl,
                        const float* __restrict__ alog,    // [1024,16] f32
                        float* __restrict__ pq) {
  int idx = blockIdx.x * 256 + threadIdx.x;   // 4*NCH*1024 = 2^18
  int d = idx & 1023;
  int c = (idx >> 10) & (NCH - 1);
  int b = idx >> 16;
  float a[16];
#pragma unroll
  for (int n = 0; n < 16; n++) a[n] = -__expf(alog[d * 16 + n]);
  float h[16], P[16];
#pragma unroll
  for (int n = 0; n < 16; n++) { h[n] = 0.f; P[n] = 1.f; }
  int mb = b * 2048 + c * LCH;
#pragma unroll 2
  for (int t = 0; t < LCH; t++) {
    int mrow = __builtin_amdgcn_readfirstlane(mb + t);       // wave-uniform row
    size_t m = (size_t)(mb + t);
    float dtv = bf2f(dt[m * 1024 + d]);
    float xv  = bf2f(xc[m * 1024 + d]);
    float dtx = dtv * xv;
    const float* bp = dbl + (size_t)mrow * 64 + 32;          // uniform -> s_load
#pragma unroll
    for (int n = 0; n < 16; n++) {
      float dA = __expf(dtv * a[n]);
      h[n] = dA * h[n] + dtx * bp[n];
      P[n] *= dA;
    }
  }
  float* o = pq + ((size_t)(b * NCH + c) * 32) * 1024 + d;
#pragma unroll
  for (int n = 0; n < 16; n++) {
    o[(size_t)n * 1024] = P[n];
    o[(size_t)(16 + n) * 1024] = h[n];
  }
}

// ---------- scan pass2: sequential chunk combine; h_init overwrites the P slot ----------
__global__ void scan_p2(float* __restrict__ pq) {
  int idx = blockIdx.x * 256 + threadIdx.x;   // 4*16*1024
  int d = idx & 1023;
  int n = (idx >> 10) & 15;
  int b = idx >> 14;
  float h = 0.f;
  for (int c = 0; c < NCH; c++) {
    size_t pbase = ((size_t)(b * NCH + c) * 32) * 1024 + d;
    float P = pq[pbase + (size_t)n * 1024];
    float q = pq[pbase + (size_t)(16 + n) * 1024];
    pq[pbase + (size_t)n * 1024] = h;          // h_init for chunk c (P no longer needed)
    h = P * h + q;
  }
}

// ---------- scan pass3: replay with h0, fuse +xc*D and *silu(z); write bf16 original time ----------
template<bool REV, bool ADD>
__global__ void scan_p3(const unsigned short* __restrict__ dt,
                        const unsigned short* __restrict__ xc,
                        const float* __restrict__ dbl,
                        const float* __restrict__ alog,
                        const float* __restrict__ Dp,              // [1024] f32
                        const unsigned short* __restrict__ xz,     // z = cols 1024..2047 (bf16)
                        const float* __restrict__ pq,              // h_init in P slots
                        unsigned short* __restrict__ ysum) {       // [B*L, 1024] bf16, original time
  int idx = blockIdx.x * 256 + threadIdx.x;
  int d = idx & 1023;
  int c = (idx >> 10) & (NCH - 1);
  int b = idx >> 16;
  float a[16];
#pragma unroll
  for (int n = 0; n < 16; n++) a[n] = -__expf(alog[d * 16 + n]);
  float h[16];
  const float* hi = pq + ((size_t)(b * NCH + c) * 32) * 1024 + d;
#pragma unroll
  for (int n = 0; n < 16; n++) h[n] = hi[(size_t)n * 1024];
  float Dv = Dp[d];
  int mb = b * 2048 + c * LCH;
#pragma unroll 2
  for (int t = 0; t < LCH; t++) {
    int mrow = __builtin_amdgcn_readfirstlane(mb + t);       // wave-uniform row
    size_t m = (size_t)(mb + t);
    float dtv = bf2f(dt[m * 1024 + d]);
    float xv  = bf2f(xc[m * 1024 + d]);
    float dtx = dtv * xv;
    const float* bp = dbl + (size_t)mrow * 64;               // uniform -> s_load
    float y = 0.f;
#pragma unroll
    for (int n = 0; n < 16; n++) {
      float dA = __expf(dtv * a[n]);
      h[n] = dA * h[n] + dtx * bp[32 + n];
      y += h[n] * bp[48 + n];
    }
    y += xv * Dv;
    int tau = c * LCH + t;
    int to = REV ? (2047 - tau) : tau;
    size_t mo = (size_t)b * 2048 + to;
    float zv = bf2f(xz[mo * 2048 + 1024 + d]);
    float gt = zv / (1.f + __expf(-zv));
    float val = y * gt;
    if (ADD) val += bf2f(ysum[mo * 1024 + d]);
    ysum[mo * 1024 + d] = f2bf(val);
  }
}

// ---------- layernorm(512) + residual; one wave per row; all f32 ----------
__global__ void ln_res_k(const float* __restrict__ yt,   // [B*L, 512] f32
                         const float* __restrict__ x,    // [B*L, 512] f32
                         const float* __restrict__ g,    // [512]
                         const float* __restrict__ bta,  // [512]
                         float* __restrict__ out) {      // [B*L, 512] f32
  int m = blockIdx.x;
  int l = threadIdx.x;   // 0..63
  const float* yr = yt + (size_t)m * 512 + l * 8;
  float vv[8];
  *(float4*)&vv[0] = *(const float4*)yr;
  *(float4*)&vv[4] = *(const float4*)(yr + 4);
  float s = 0.f, ss = 0.f;
#pragma unroll
  for (int j = 0; j < 8; j++) { s += vv[j]; ss += vv[j] * vv[j]; }
#pragma unroll
  for (int o = 32; o > 0; o >>= 1) { s += __shfl_xor(s, o); ss += __shfl_xor(ss, o); }
  float mu = s * (1.f / 512.f);
  float var = ss * (1.f / 512.f) - mu * mu;
  float rstd = rsqrtf(var + 1e-6f);
  const float* xr = x + (size_t)m * 512 + l * 8;
  float xv[8];
  *(float4*)&xv[0] = *(const float4*)xr;
  *(float4*)&xv[4] = *(const float4*)(xr + 4);
  float ov[8];
#pragma unroll
  for (int j = 0; j < 8; j++) {
    int d = l * 8 + j;
    ov[j] = xv[j] + (vv[j] - mu) * rstd * g[d] + bta[d];
  }
  float* orow = out + (size_t)m * 512 + l * 8;
  *(float4*)orow = *(float4*)&ov[0];
  *(float4*)(orow + 4) = *(float4*)&ov[4];
}

// ---------- launcher ----------
extern "C" void kernel_launch(void* const* d_in, const int* in_sizes, int n_in,
                              void* d_out, int out_size, void* d_ws, size_t ws_size,
                              hipStream_t stream) {
  const float* x_f32   = (const float*)d_in[0];
  const float* w_in_f  = (const float*)d_in[1];
  const float* w_out_f = (const float*)d_in[2];
  const float* ln_g    = (const float*)d_in[17];
  const float* ln_b    = (const float*)d_in[18];

  char* ws = (char*)d_ws;
  unsigned short* XB   = (unsigned short*)(ws + 0);           // [8192,512] bf16    8 MiB
  unsigned short* W1B  = (unsigned short*)(ws + 8388608);     // [2048,512] bf16    2 MiB
  unsigned short* W2B  = (unsigned short*)(ws + 10485760);    // [512,1024] bf16    1 MiB
  unsigned short* XPB  = (unsigned short*)(ws + 11534336);    // [64,1024]  bf16  128 KiB
  unsigned short* XZ   = (unsigned short*)(ws + 11665408);    // [8192,2048] bf16  32 MiB
  unsigned short* XC   = (unsigned short*)(ws + 45219840);    // [8192,1024] bf16  16 MiB
  unsigned short* DT   = (unsigned short*)(ws + 61997056);    // [8192,1024] bf16  16 MiB
  float*          DBL  = (float*)(ws + 78774272);             // [8192,64]  f32     2 MiB
  unsigned short* YSB  = (unsigned short*)(ws + 80871424);    // [8192,1024] bf16  16 MiB
  float*          PQ   = (float*)(ws + 97648640);             // [4][64][32][1024] f32  32 MiB
  float*          YT   = PQ;                                  // reuse PQ after scans (16 MiB)
  // total: 131,203,072 B = 125.1 MiB

  const int M = 8192;

  // convert GEMM operands to bf16
  cvt_f2bf_k<<<4096, 256, 0, stream>>>(x_f32, XB);        // 8192*512
  cvt_f2bf_k<<<1024, 256, 0, stream>>>(w_in_f, W1B);      // 2048*512
  cvt_f2bf_k<<< 512, 256, 0, stream>>>(w_out_f, W2B);     // 512*1024

  // xz = x @ in_proj_w^T   [8192, 2048]
  gemm_bt<128, 128, 2, 2, false><<<dim3(64, 16), 256, 0, stream>>>(XB, W1B, (void*)XZ, M, 2048, 512);

  for (int br = 0; br < 2; br++) {
    const float* cw    = (const float*)d_in[3 + br * 7];
    const float* cb    = (const float*)d_in[4 + br * 7];
    const float* xproj = (const float*)d_in[5 + br * 7];
    const float* dtw   = (const float*)d_in[6 + br * 7];
    const float* dtb   = (const float*)d_in[7 + br * 7];
    const float* alog  = (const float*)d_in[8 + br * 7];
    const float* Dp    = (const float*)d_in[9 + br * 7];

    cvt_f2bf_k<<<64, 256, 0, stream>>>(xproj, XPB);       // 64*1024

    if (br == 0) conv_silu_k<false><<<32768, 256, 0, stream>>>(XZ, cw, cb, XC);
    else         conv_silu_k<true ><<<32768, 256, 0, stream>>>(XZ, cw, cb, XC);

    // dbl = xc @ xproj^T  [8192, 64]
    gemm_bt<128, 64, 4, 1, true><<<dim3(64, 1), 256, 0, stream>>>(XC, XPB, (void*)DBL, M, 64, 1024);

    // dt = softplus(dbl[:, :32] @ dtw^T + dtb)
    dtproj_k<<<dim3(8192 / DROWS, 4), 256, 0, stream>>>(DBL, dtw, dtb, DT);

    scan_p1<<<1024, 256, 0, stream>>>(DT, XC, DBL, alog, PQ);
    scan_p2<<<256, 256, 0, stream>>>(PQ);
    if (br == 0) scan_p3<false, false><<<1024, 256, 0, stream>>>(DT, XC, DBL, alog, Dp, XZ, PQ, YSB);
    else         scan_p3<true,  true ><<<1024, 256, 0, stream>>>(DT, XC, DBL, alog, Dp, XZ, PQ, YSB);
  }

  // yt = ysum(bf16) @ out_proj^T  [8192, 512] f32 (into YT = PQ region)
  gemm_bt<128, 128, 2, 2, true><<<dim3(64, 4), 256, 0, stream>>>(YSB, W2B, (void*)YT, M, 512, 1024);

  // out = x + layernorm(yt)
  ln_res_k<<<8192, 64, 0, stream>>>(YT, x_f32, ln_g, ln_b, (float*)d_out);
}